// Round 9
// baseline (178.713 us; speedup 1.0000x reference)
//
#include <hip/hip_runtime.h>
#include <hip/hip_bf16.h>

// Head: out[b,t,h] = softmax_causal( (x@Wq)(x@Wk)^T * 6^-0.5 ) @ (x@Wv)
// B=512 T=128 C=384 H=64. One block per b, bf16 MFMA 16x16x32.
//
// V9: linear whole-tile x read (kill the strided-segment stream).
//  - V1-V8 all read x in 128B segments @1536B stride (k-chunked), and all
//    landed ~55-77us regardless of sync scheme; V7 depth-3 == V5 depth-1
//    -> bandwidth/efficiency-bound, not latency-bound. Fix the stream itself.
//  - Each thread: 24 contiguous dwordx4 loads (block = one linear 196KB
//    burst, same shape as the 6.8TB/s fill kernel), cvt to bf16 in regs,
//    swizzled ds_write_b128 into a RESIDENT x image (98.3KB LDS). ONE barrier.
//  - k-loop: no barriers, no global x. A-frags = 1 conflict-free ds_read_b128
//    (already bf16; deletes 32 cvts/iter). Wt = register-prefetched global
//    loads, the only VMEM in the loop (clean FIFO; L2-hot, 144KB shared).
//  - LDS 98.3KB -> 1 block/CU; grid 512 = 2 staggered block-waves/CU
//    (load phase of one overlaps compute of the other).
//  - Epilogue/phase-2 = V5 verbatim, overwriting the dead x region.

#define B_ 512
#define T_ 128
#define C_ 384
#define H_ 64

typedef __bf16 bf16;
typedef __attribute__((ext_vector_type(8))) __bf16 bf16x8;
typedef __attribute__((ext_vector_type(4))) __bf16 bf16x4;
typedef __attribute__((ext_vector_type(4))) float f32x4;

// ---------------- pre-kernel: W -> bf16 W^T in MFMA B-fragment order --------
// Wt[((kc*12 + tn)*64 + lane)*8 + e] = Wsel[(kc*32 + quad*8 + e)*64 + h]
__global__ void build_wt(const float* __restrict__ Wq, const float* __restrict__ Wk,
                         const float* __restrict__ Wv, bf16* __restrict__ Wt)
{
    int t = blockIdx.x * 256 + threadIdx.x;
    if (t >= 12 * 12 * 64) return;
    int lane = t & 63;
    int tn   = (t >> 6) % 12;
    int kc   = t / (12 * 64);
    int lm = lane & 15, quad = lane >> 4;
    int n = tn * 16 + lm;
    int j = n >> 6, h = n & 63;
    const float* Wp = (j == 0) ? Wq : (j == 1) ? Wk : Wv;
    int k0 = kc * 32 + quad * 8;
    bf16x8 v;
#pragma unroll
    for (int e = 0; e < 8; ++e) v[e] = (bf16)Wp[(k0 + e) * H_ + h];
    *(bf16x8*)&Wt[t * 8] = v;
}

// LDS (98304 bytes -> 1 block/CU):
//  phase 1: x image, bf16 [128 rows][48 16B-units], XOR-swizzled:
//           phys = (u16 & ~7) | ((u16 ^ row) & 7); elem = row*384 + phys*8
//  after:   Qs [0,8192) elems, Ks [8192,16384), Vts [16384,24576),
//           Ps aliases [0,16384)   (x image is dead; region overwritten)

__launch_bounds__(512, 2)
__global__ void head_fused(const float* __restrict__ x,
                           const bf16* __restrict__ Wt,
                           float* __restrict__ out)
{
    __shared__ __align__(16) bf16 lds[49152];   // 98304 B
    bf16* Qs  = lds;
    bf16* Ks  = lds + 8192;
    bf16* Vts = lds + 16384;
    bf16* Ps  = lds;

    const int tid  = threadIdx.x;
    const int w    = tid >> 6;     // wave 0..7
    const int lane = tid & 63;
    const int lm   = lane & 15;
    const int quad = lane >> 4;
    const int mg   = w >> 2;       // m-group 0..1 (64 rows each)
    const int ng   = w & 3;        // n-group 0..3 (3 tiles each)
    const int b    = blockIdx.x;

    // ========== Phase 1a: linear x[b] load -> bf16 -> swizzled LDS ==========
    // thread t owns fp32 16B-units [t*24, t*24+24) = row t>>2, fp32 cols
    // [(t&3)*96, +96). Loads are contiguous per thread; block covers the
    // whole 196KB tile linearly.
    const float4* xb4 = (const float4*)(x + (size_t)b * (T_ * C_));
    float4 xv[24];
#pragma unroll
    for (int j = 0; j < 24; ++j) xv[j] = xb4[tid * 24 + j];

    // prefetch Wt chunk 0 fragments (behind x loads in FIFO; needed after
    // the barrier, by which time x loads have retired anyway)
    const bf16* wl = Wt + (size_t)(3 * ng) * 512 + lane * 8;
    bf16x8 wc0 = *(const bf16x8*)(wl);
    bf16x8 wc1 = *(const bf16x8*)(wl + 512);
    bf16x8 wc2 = *(const bf16x8*)(wl + 1024);

    {
        const int row = tid >> 2;          // 0..127 (constant per thread)
        const int u0  = (tid & 3) * 12;    // bf16 16B-unit base 0..36
#pragma unroll
        for (int jp = 0; jp < 12; ++jp) {
            float4 a = xv[2 * jp], c = xv[2 * jp + 1];
            bf16x8 v = {(bf16)a.x, (bf16)a.y, (bf16)a.z, (bf16)a.w,
                        (bf16)c.x, (bf16)c.y, (bf16)c.z, (bf16)c.w};
            int u16  = u0 + jp;
            int phys = (u16 & ~7) | ((u16 ^ row) & 7);
            *(bf16x8*)&lds[row * 384 + phys * 8] = v;
        }
    }
    // own ds_writes drained, then barrier: x image visible to all.
    // (plain s_barrier, NOT __syncthreads: keep Wt chunk-0 loads in flight)
    asm volatile("s_waitcnt lgkmcnt(0)" ::: "memory");
    __builtin_amdgcn_s_barrier();

    // ========== Phase 1b: QKV k-loop — no barriers, no global x ==========
    f32x4 acc[4][3];
#pragma unroll
    for (int mf = 0; mf < 4; ++mf)
#pragma unroll
        for (int nf = 0; nf < 3; ++nf) acc[mf][nf] = (f32x4){0.f, 0.f, 0.f, 0.f};

#pragma unroll
    for (int kc = 0; kc < 12; ++kc) {
        bf16x8 wn0 = wc0, wn1 = wc1, wn2 = wc2;
        if (kc < 11) {   // register-prefetch next Wt chunk (only VMEM in loop)
            const bf16* wp = wl + (size_t)(kc + 1) * 6144;
            wn0 = *(const bf16x8*)(wp);
            wn1 = *(const bf16x8*)(wp + 512);
            wn2 = *(const bf16x8*)(wp + 1024);
        }
        bf16x8 afr[4];
#pragma unroll
        for (int mf = 0; mf < 4; ++mf) {
            int row  = 64 * mg + 16 * mf + lm;
            int u16  = kc * 4 + quad;
            int phys = (u16 & ~7) | ((u16 ^ row) & 7);
            afr[mf] = *(const bf16x8*)&lds[row * 384 + phys * 8];
        }
#pragma unroll
        for (int mf = 0; mf < 4; ++mf) {
            acc[mf][0] = __builtin_amdgcn_mfma_f32_16x16x32_bf16(afr[mf], wc0, acc[mf][0], 0, 0, 0);
            acc[mf][1] = __builtin_amdgcn_mfma_f32_16x16x32_bf16(afr[mf], wc1, acc[mf][1], 0, 0, 0);
            acc[mf][2] = __builtin_amdgcn_mfma_f32_16x16x32_bf16(afr[mf], wc2, acc[mf][2], 0, 0, 0);
        }
        wc0 = wn0; wc1 = wn1; wc2 = wn2;
    }
    __syncthreads();   // x image dead; Q/K/Vt region becomes live

    // epilogue: Q,K row-major [t][h]; V transposed [h][t]; all swizzled bf16
#pragma unroll
    for (int mf = 0; mf < 4; ++mf) {
#pragma unroll
        for (int nf = 0; nf < 3; ++nf) {
            int tn = 3 * ng + nf;
            int gn = 16 * tn + lm;
            int j = gn >> 6, h = gn & 63;
            int m0 = 64 * mg + 16 * mf + quad * 4;
            if (j == 2) {
                bf16x4 v4 = {(bf16)acc[mf][nf][0], (bf16)acc[mf][nf][1],
                             (bf16)acc[mf][nf][2], (bf16)acc[mf][nf][3]};
                int pc = (m0 & 7) | ((((m0 >> 3) ^ (h & 15)) & 15) << 3);
                *(bf16x4*)&Vts[h * 128 + pc] = v4;
            } else {
                bf16* dst = (j == 0) ? Qs : Ks;
#pragma unroll
                for (int r = 0; r < 4; ++r) {
                    int m = m0 + r;
                    int pc = (h & 7) | ((((h >> 3) ^ (m & 7)) & 7) << 3);
                    dst[m * 64 + pc] = (bf16)acc[mf][nf][r];
                }
            }
        }
    }
    __syncthreads();

    // ================= Phase 2: attention =================
    const float SCALE = 0.40824829046386307f;  // 6^-0.5
    const int tm = w;
    const int mrow = 16 * tm + lm;

    f32x4 sacc[8];
#pragma unroll
    for (int t = 0; t < 8; ++t) sacc[t] = (f32x4){0.f, 0.f, 0.f, 0.f};

    bf16x8 qa[2];
#pragma unroll
    for (int ks = 0; ks < 2; ++ks) {
        int phys = ((ks * 4 + quad) ^ (mrow & 7)) & 7;
        qa[ks] = *(const bf16x8*)&Qs[mrow * 64 + phys * 8];
    }
#pragma unroll
    for (int tn = 0; tn < 8; ++tn) {
        if (tn <= tm) {
            int nrow = 16 * tn + lm;
#pragma unroll
            for (int ks = 0; ks < 2; ++ks) {
                int phys = ((ks * 4 + quad) ^ (nrow & 7)) & 7;
                bf16x8 kb = *(const bf16x8*)&Ks[nrow * 64 + phys * 8];
                sacc[tn] =
                    __builtin_amdgcn_mfma_f32_16x16x32_bf16(qa[ks], kb, sacc[tn], 0, 0, 0);
            }
        }
    }

    // softmax, fully in registers
#pragma unroll
    for (int r = 0; r < 4; ++r) {
        int m = 16 * tm + quad * 4 + r;
        float mx = -1e30f;
#pragma unroll
        for (int tn = 0; tn < 8; ++tn) {
            if (tn <= tm) {
                int n = 16 * tn + lm;
                float v = (n <= m) ? sacc[tn][r] * SCALE : -1e30f;
                sacc[tn][r] = v;
                mx = fmaxf(mx, v);
            }
        }
#pragma unroll
        for (int off = 1; off < 16; off <<= 1) mx = fmaxf(mx, __shfl_xor(mx, off, 16));
        float sum = 0.f;
#pragma unroll
        for (int tn = 0; tn < 8; ++tn) {
            if (tn <= tm) {
                float e = __expf(sacc[tn][r] - mx);
                sacc[tn][r] = e;
                sum += e;
            }
        }
#pragma unroll
        for (int off = 1; off < 16; off <<= 1) sum += __shfl_xor(sum, off, 16);
        float inv = 1.f / sum;
#pragma unroll
        for (int tn = 0; tn < 8; ++tn) {
            if (tn <= tm) sacc[tn][r] *= inv;
        }
    }

    __syncthreads();  // everyone done reading Qs/Ks; Ps aliases them

    // write P (bf16, swizzled); each wave writes only its own rows
#pragma unroll
    for (int tn = 0; tn < 8; ++tn) {
        if (tn <= tm) {
            int n = 16 * tn + lm;
#pragma unroll
            for (int r = 0; r < 4; ++r) {
                int m = 16 * tm + quad * 4 + r;
                int pc = (n & 7) | ((((n >> 3) ^ (m & 15)) & 15) << 3);
                Ps[m * 128 + pc] = (bf16)sacc[tn][r];
            }
        }
    }
    if ((tm & 1) == 0) {  // zero the half-covered k-tile (tm even)
        int m = 16 * tm + lm;
        int c0 = 16 * (tm + 1) + quad * 4;
        int pc = (c0 & 7) | ((((c0 >> 3) ^ (m & 15)) & 15) << 3);
        *(bf16x4*)&Ps[m * 128 + pc] =
            (bf16x4){(bf16)0.f, (bf16)0.f, (bf16)0.f, (bf16)0.f};
    }

    // O = P @ V  (reads only own P rows -> no barrier needed before PV)
    f32x4 oacc[4];
#pragma unroll
    for (int t = 0; t < 4; ++t) oacc[t] = (f32x4){0.f, 0.f, 0.f, 0.f};

    const int nks = (tm + 2) >> 1;
    for (int ks = 0; ks < nks; ++ks) {  // wave-uniform bound
        int unit = ks * 4 + quad;
        int phys = (unit ^ (mrow & 15)) & 15;
        bf16x8 pa = *(const bf16x8*)&Ps[mrow * 128 + phys * 8];
#pragma unroll
        for (int th = 0; th < 4; ++th) {
            int hrow = 16 * th + lm;
            int ph2 = (unit ^ (hrow & 15)) & 15;
            bf16x8 vb = *(const bf16x8*)&Vts[hrow * 128 + ph2 * 8];
            oacc[th] =
                __builtin_amdgcn_mfma_f32_16x16x32_bf16(pa, vb, oacc[th], 0, 0, 0);
        }
    }

    // store O fp32 [b][t][h]
    float* ob = out + (size_t)b * (T_ * H_);
#pragma unroll
    for (int th = 0; th < 4; ++th) {
        int h = 16 * th + lm;
#pragma unroll
        for (int r = 0; r < 4; ++r) {
            int m = 16 * tm + quad * 4 + r;
            ob[m * 64 + h] = oacc[th][r];
        }
    }
}

extern "C" void kernel_launch(void* const* d_in, const int* in_sizes, int n_in,
                              void* d_out, int out_size, void* d_ws, size_t ws_size,
                              hipStream_t stream) {
    const float* x  = (const float*)d_in[0];
    const float* Wq = (const float*)d_in[1];
    const float* Wk = (const float*)d_in[2];
    const float* Wv = (const float*)d_in[3];
    float* o = (float*)d_out;
    bf16* Wt = (bf16*)d_ws;   // needs 147456 bytes
    build_wt<<<dim3(36), dim3(256), 0, stream>>>(Wq, Wk, Wv, Wt);
    head_fused<<<dim3(B_), dim3(512), 0, stream>>>(x, Wt, o);
}

// Round 10
// 173.213 us; speedup vs baseline: 1.0318x; 1.0318x over previous
//
#include <hip/hip_runtime.h>
#include <hip/hip_bf16.h>

// Head: out[b,t,h] = softmax_causal( (x@Wq)(x@Wk)^T * 6^-0.5 ) @ (x@Wv)
// B=512 T=128 C=384 H=64. bf16 MFMA 16x16x32.
//
// V10: 2 batches per block — halve Wt delivery traffic, double work/chunk.
//  - Evidence: time invariant to HBM-vs-L3 source (V9 warm pass: 64us @ 260
//    GB/s), to pipeline depth (V5==V7), to phase 2 (4us, V8); correlates with
//    total bytes delivered to CUs (V3 4x-reads=76us vs V5 1x=55us). Wt
//    re-reads were 74MB/iter (~40% of delivered bytes) -> merge b-pairs.
//  - 256 blocks, each does b0=2*bid, b1=2*bid+1. k-loop stages
//    {x0 16KB, x1 16KB, Wt 12KB} per chunk, 2 buffers, vmcnt(0)+s_barrier
//    (V5's proven protocol). One Wt fragment feeds BOTH batches: 24 MFMA
//    per chunk vs 12, same staged Wt.
//  - LDS 96KB: staging [0,90112) during k-loop; then two 48KB Q/K/Vt images
//    at [0,49152) and [49152,98304) overwrite it. Epilogue+attention x2.
//  - 1 block/CU (96KB), 8 waves. Occupancy was proven a non-lever (V3).

#define B_ 512
#define T_ 128
#define C_ 384
#define H_ 64

typedef __bf16 bf16;
typedef __attribute__((ext_vector_type(8))) __bf16 bf16x8;
typedef __attribute__((ext_vector_type(4))) __bf16 bf16x4;
typedef __attribute__((ext_vector_type(4))) float f32x4;

#define GLOAD_LDS16(g, l)                                                     \
    __builtin_amdgcn_global_load_lds(                                         \
        (const __attribute__((address_space(1))) void*)(g),                   \
        (__attribute__((address_space(3))) void*)(l), 16, 0, 0)

// ---------------- pre-kernel: W -> bf16 W^T in MFMA B-fragment order --------
// Wt[((kc*12 + tn)*64 + lane)*8 + e] = Wsel[(kc*32 + quad*8 + e)*64 + h]
__global__ void build_wt(const float* __restrict__ Wq, const float* __restrict__ Wk,
                         const float* __restrict__ Wv, bf16* __restrict__ Wt)
{
    int t = blockIdx.x * 256 + threadIdx.x;
    if (t >= 12 * 12 * 64) return;
    int lane = t & 63;
    int tn   = (t >> 6) % 12;
    int kc   = t / (12 * 64);
    int lm = lane & 15, quad = lane >> 4;
    int n = tn * 16 + lm;
    int j = n >> 6, h = n & 63;
    const float* Wp = (j == 0) ? Wq : (j == 1) ? Wk : Wv;
    int k0 = kc * 32 + quad * 8;
    bf16x8 v;
#pragma unroll
    for (int e = 0; e < 8; ++e) v[e] = (bf16)Wp[(k0 + e) * H_ + h];
    *(bf16x8*)&Wt[t * 8] = v;
}

// LDS (98304 bytes -> 1 block/CU):
//  k-loop, buffer p in {0,1} at byte p*45056:
//    x0 [+0,+16384) x1 [+16384,+32768) : 128 rows x 8 swizzled 16B units (fp32)
//    Wt [+32768,+45056)                : linear 12KB Wt chunk
//  after k-loop: image g in {0,1} at byte g*49152 (elem g*24576):
//    Qs [+0,8192) elems, Ks [+8192,16384), Vts [+16384,24576), Ps aliases Qs/Ks

__launch_bounds__(512, 2)
__global__ void head_fused(const float* __restrict__ x,
                           const bf16* __restrict__ Wt,
                           float* __restrict__ out)
{
    __shared__ __align__(16) bf16 lds[49152];   // 98304 B

    const int tid  = threadIdx.x;
    const int w    = tid >> 6;     // wave 0..7
    const int lane = tid & 63;
    const int lm   = lane & 15;
    const int quad = lane >> 4;
    const int mg   = w >> 2;       // m-group 0..1 (64 rows each)
    const int ng   = w & 3;        // n-group 0..3 (3 tiles each)
    const int b0   = 2 * blockIdx.x;

    const float* xb0 = x + (size_t)b0 * (T_ * C_);
    const float* xb1 = xb0 + (T_ * C_);

    // ================= Phase 1: QKV for b0 AND b1 =================
    f32x4 acc[2][4][3];
#pragma unroll
    for (int g = 0; g < 2; ++g)
#pragma unroll
        for (int mf = 0; mf < 4; ++mf)
#pragma unroll
            for (int nf = 0; nf < 3; ++nf) acc[g][mf][nf] = (f32x4){0.f, 0.f, 0.f, 0.f};

    // staging addresses (V5 scheme per x-tile): unit u holds global
    // (row=u>>3, srcunit=(u&7)^(row&7)); thread t stages units t and t+512.
    const int r0 = tid >> 3, r1 = (tid + 512) >> 3;
    const int c0 = ((tid & 7) ^ (r0 & 7)) * 4, c1 = ((tid & 7) ^ (r1 & 7)) * 4;
    const float* g0a = xb0 + (size_t)r0 * C_ + c0;
    const float* g0b = xb0 + (size_t)r1 * C_ + c1;
    const float* g1a = xb1 + (size_t)r0 * C_ + c0;
    const float* g1b = xb1 + (size_t)r1 * C_ + c1;
    char* l0a = (char*)lds + w * 1024;
    char* l0b = (char*)lds + 8192 + w * 1024;
    char* l1a = (char*)lds + 16384 + w * 1024;
    char* l1b = (char*)lds + 24576 + w * 1024;
    const char* gwt = (const char*)Wt;
    char* lwa = (char*)lds + 32768 + w * 1024;
    char* lwb = (char*)lds + 32768 + 8192 + w * 1024;

    auto STAGE = [&](int kc) {
        int bo = (kc & 1) * 45056;
        GLOAD_LDS16(g0a + kc * 32, l0a + bo);
        GLOAD_LDS16(g0b + kc * 32, l0b + bo);
        GLOAD_LDS16(g1a + kc * 32, l1a + bo);
        GLOAD_LDS16(g1b + kc * 32, l1b + bo);
        GLOAD_LDS16(gwt + (size_t)kc * 12288 + tid * 16, lwa + bo);
        if (w < 4)
            GLOAD_LDS16(gwt + (size_t)kc * 12288 + 8192 + tid * 16, lwb + bo);
    };

    STAGE(0);
    asm volatile("s_waitcnt vmcnt(0)" ::: "memory");
    __builtin_amdgcn_s_barrier();

#pragma unroll
    for (int kc = 0; kc < 12; ++kc) {
        if (kc < 11) STAGE(kc + 1);

        const char* bufc = (const char*)lds + (kc & 1) * 45056;
        const float* xc0 = (const float*)bufc;
        const float* xc1 = (const float*)(bufc + 16384);
        const bf16*  wc  = (const bf16*)(bufc + 32768);

        bf16x8 bfr[3];
#pragma unroll
        for (int nf = 0; nf < 3; ++nf)
            bfr[nf] = *(const bf16x8*)(wc + (3 * ng + nf) * 512 + lane * 8);

        bf16x8 afr0[4], afr1[4];
#pragma unroll
        for (int mf = 0; mf < 4; ++mf) {
            int row = 64 * mg + 16 * mf + lm;
            int p0 = (2 * quad) ^ (row & 7);
            int p1 = (2 * quad + 1) ^ (row & 7);
            f32x4 va = *(const f32x4*)(xc0 + row * 32 + p0 * 4);
            f32x4 vb = *(const f32x4*)(xc0 + row * 32 + p1 * 4);
            afr0[mf] = (bf16x8){(bf16)va[0], (bf16)va[1], (bf16)va[2], (bf16)va[3],
                                (bf16)vb[0], (bf16)vb[1], (bf16)vb[2], (bf16)vb[3]};
            f32x4 vc = *(const f32x4*)(xc1 + row * 32 + p0 * 4);
            f32x4 vd = *(const f32x4*)(xc1 + row * 32 + p1 * 4);
            afr1[mf] = (bf16x8){(bf16)vc[0], (bf16)vc[1], (bf16)vc[2], (bf16)vc[3],
                                (bf16)vd[0], (bf16)vd[1], (bf16)vd[2], (bf16)vd[3]};
        }
#pragma unroll
        for (int nf = 0; nf < 3; ++nf) {
#pragma unroll
            for (int mf = 0; mf < 4; ++mf) {
                acc[0][mf][nf] = __builtin_amdgcn_mfma_f32_16x16x32_bf16(
                    afr0[mf], bfr[nf], acc[0][mf][nf], 0, 0, 0);
                acc[1][mf][nf] = __builtin_amdgcn_mfma_f32_16x16x32_bf16(
                    afr1[mf], bfr[nf], acc[1][mf][nf], 0, 0, 0);
            }
        }

        if (kc < 11) {
            asm volatile("s_waitcnt vmcnt(0)" ::: "memory");
            __builtin_amdgcn_s_barrier();
        }
    }
    __syncthreads();   // staging dies; image regions become live

    // epilogue x2: Q,K row-major [t][h]; V transposed [h][t]; swizzled bf16
#pragma unroll
    for (int g = 0; g < 2; ++g) {
        bf16* img = lds + g * 24576;
        bf16* Qs  = img;
        bf16* Ks  = img + 8192;
        bf16* Vts = img + 16384;
#pragma unroll
        for (int mf = 0; mf < 4; ++mf) {
#pragma unroll
            for (int nf = 0; nf < 3; ++nf) {
                int tn = 3 * ng + nf;
                int gn = 16 * tn + lm;
                int j = gn >> 6, h = gn & 63;
                int m0 = 64 * mg + 16 * mf + quad * 4;
                if (j == 2) {
                    bf16x4 v4 = {(bf16)acc[g][mf][nf][0], (bf16)acc[g][mf][nf][1],
                                 (bf16)acc[g][mf][nf][2], (bf16)acc[g][mf][nf][3]};
                    int pc = (m0 & 7) | ((((m0 >> 3) ^ (h & 15)) & 15) << 3);
                    *(bf16x4*)&Vts[h * 128 + pc] = v4;
                } else {
                    bf16* dst = (j == 0) ? Qs : Ks;
#pragma unroll
                    for (int r = 0; r < 4; ++r) {
                        int m = m0 + r;
                        int pc = (h & 7) | ((((h >> 3) ^ (m & 7)) & 7) << 3);
                        dst[m * 64 + pc] = (bf16)acc[g][mf][nf][r];
                    }
                }
            }
        }
    }
    __syncthreads();

    // ================= Phase 2: attention, x2 =================
    const float SCALE = 0.40824829046386307f;  // 6^-0.5
    const int tm = w;
    const int mrow = 16 * tm + lm;

#pragma unroll
    for (int g = 0; g < 2; ++g) {
        bf16* img = lds + g * 24576;
        bf16* Qs  = img;
        bf16* Ks  = img + 8192;
        bf16* Vts = img + 16384;
        bf16* Ps  = img;

        f32x4 sacc[8];
#pragma unroll
        for (int t = 0; t < 8; ++t) sacc[t] = (f32x4){0.f, 0.f, 0.f, 0.f};

        bf16x8 qa[2];
#pragma unroll
        for (int ks = 0; ks < 2; ++ks) {
            int phys = ((ks * 4 + quad) ^ (mrow & 7)) & 7;
            qa[ks] = *(const bf16x8*)&Qs[mrow * 64 + phys * 8];
        }
#pragma unroll
        for (int tn = 0; tn < 8; ++tn) {
            if (tn <= tm) {
                int nrow = 16 * tn + lm;
#pragma unroll
                for (int ks = 0; ks < 2; ++ks) {
                    int phys = ((ks * 4 + quad) ^ (nrow & 7)) & 7;
                    bf16x8 kb = *(const bf16x8*)&Ks[nrow * 64 + phys * 8];
                    sacc[tn] =
                        __builtin_amdgcn_mfma_f32_16x16x32_bf16(qa[ks], kb, sacc[tn], 0, 0, 0);
                }
            }
        }

        // softmax, fully in registers
#pragma unroll
        for (int r = 0; r < 4; ++r) {
            int m = 16 * tm + quad * 4 + r;
            float mx = -1e30f;
#pragma unroll
            for (int tn = 0; tn < 8; ++tn) {
                if (tn <= tm) {
                    int n = 16 * tn + lm;
                    float v = (n <= m) ? sacc[tn][r] * SCALE : -1e30f;
                    sacc[tn][r] = v;
                    mx = fmaxf(mx, v);
                }
            }
#pragma unroll
            for (int off = 1; off < 16; off <<= 1) mx = fmaxf(mx, __shfl_xor(mx, off, 16));
            float sum = 0.f;
#pragma unroll
            for (int tn = 0; tn < 8; ++tn) {
                if (tn <= tm) {
                    float e = __expf(sacc[tn][r] - mx);
                    sacc[tn][r] = e;
                    sum += e;
                }
            }
#pragma unroll
            for (int off = 1; off < 16; off <<= 1) sum += __shfl_xor(sum, off, 16);
            float inv = 1.f / sum;
#pragma unroll
            for (int tn = 0; tn < 8; ++tn) {
                if (tn <= tm) sacc[tn][r] *= inv;
            }
        }

        __syncthreads();  // everyone done reading this image's Qs/Ks; Ps aliases

        // write P (bf16, swizzled); each wave writes only its own rows
#pragma unroll
        for (int tn = 0; tn < 8; ++tn) {
            if (tn <= tm) {
                int n = 16 * tn + lm;
#pragma unroll
                for (int r = 0; r < 4; ++r) {
                    int m = 16 * tm + quad * 4 + r;
                    int pc = (n & 7) | ((((n >> 3) ^ (m & 15)) & 15) << 3);
                    Ps[m * 128 + pc] = (bf16)sacc[tn][r];
                }
            }
        }
        if ((tm & 1) == 0) {  // zero the half-covered k-tile (tm even)
            int m = 16 * tm + lm;
            int cc = 16 * (tm + 1) + quad * 4;
            int pc = (cc & 7) | ((((cc >> 3) ^ (m & 15)) & 15) << 3);
            *(bf16x4*)&Ps[m * 128 + pc] =
                (bf16x4){(bf16)0.f, (bf16)0.f, (bf16)0.f, (bf16)0.f};
        }

        // O = P @ V  (reads only own P rows -> no barrier needed before PV)
        f32x4 oacc[4];
#pragma unroll
        for (int t = 0; t < 4; ++t) oacc[t] = (f32x4){0.f, 0.f, 0.f, 0.f};

        const int nks = (tm + 2) >> 1;
        for (int ks = 0; ks < nks; ++ks) {  // wave-uniform bound
            int unit = ks * 4 + quad;
            int phys = (unit ^ (mrow & 15)) & 15;
            bf16x8 pa = *(const bf16x8*)&Ps[mrow * 128 + phys * 8];
#pragma unroll
            for (int th = 0; th < 4; ++th) {
                int hrow = 16 * th + lm;
                int ph2 = (unit ^ (hrow & 15)) & 15;
                bf16x8 vb = *(const bf16x8*)&Vts[hrow * 128 + ph2 * 8];
                oacc[th] =
                    __builtin_amdgcn_mfma_f32_16x16x32_bf16(pa, vb, oacc[th], 0, 0, 0);
            }
        }

        // store O fp32 [b][t][h]
        float* ob = out + (size_t)(b0 + g) * (T_ * H_);
#pragma unroll
        for (int th = 0; th < 4; ++th) {
            int h = 16 * th + lm;
#pragma unroll
            for (int r = 0; r < 4; ++r) {
                int m = 16 * tm + quad * 4 + r;
                ob[m * 64 + h] = oacc[th][r];
            }
        }
    }
}

extern "C" void kernel_launch(void* const* d_in, const int* in_sizes, int n_in,
                              void* d_out, int out_size, void* d_ws, size_t ws_size,
                              hipStream_t stream) {
    const float* x  = (const float*)d_in[0];
    const float* Wq = (const float*)d_in[1];
    const float* Wk = (const float*)d_in[2];
    const float* Wv = (const float*)d_in[3];
    float* o = (float*)d_out;
    bf16* Wt = (bf16*)d_ws;   // needs 147456 bytes
    build_wt<<<dim3(36), dim3(256), 0, stream>>>(Wq, Wk, Wv, Wt);
    head_fused<<<dim3(B_ / 2), dim3(512), 0, stream>>>(x, Wt, o);
}